// Round 5
// baseline (490.999 us; speedup 1.0000x reference)
//
#include <hip/hip_runtime.h>

// Causal GQA flash-attention fwd, fp32 I/O, bf16 32x32x16 MFMA, split-K.
// Prepass: K/V fp32 -> bf16 swizzled 32-key tile images in d_ws (once).
// Main: 2048 blocks x 256 thr; block = 2 row-waves x 2 key-groups (QT=64,
// split-K halves), single-buffered 16KiB/group LDS staging via
// global_load_lds, swapped-operand S^T=K*Q^T / O^T=V^T*P^T (lane-local
// softmax), end-of-block split-K combine through LDS, LPT heavy-first grid.

typedef __bf16 bf16_t;
typedef __bf16 bf16x2 __attribute__((ext_vector_type(2)));
typedef __bf16 bf16x8 __attribute__((ext_vector_type(8)));
typedef float f32x4v __attribute__((ext_vector_type(4)));
typedef float f32x16 __attribute__((ext_vector_type(16)));
typedef unsigned int u32;
typedef u32 u32x4 __attribute__((ext_vector_type(4)));

constexpr int B_ = 2, HQ = 32, HK = 8, SQ = 2048, D = 128;
constexpr int QT = 64, KT = 32;
constexpr int NQT = SQ / QT;                  // 32 q-tiles
constexpr int NT = SQ / KT;                   // 64 kv tiles per (b,hk)
constexpr int TILE_ELEM = KT * D * 2;         // 8192 bf16 = K(4096) + V(4096)
constexpr size_t TILE_BYTES = TILE_ELEM * 2;  // 16 KiB
constexpr size_t WS_NEED = (size_t)B_ * HK * NT * TILE_BYTES;  // 16 MiB

__device__ __forceinline__ u32 pkbf(float a, float b) {  // f32x2 -> bf16x2
  bf16x2 t; t[0] = (bf16_t)a; t[1] = (bf16_t)b;
  return __builtin_bit_cast(u32, t);
}
__device__ __forceinline__ float fexp2(float x) { return __builtin_exp2f(x); }

__device__ __forceinline__ void gl_lds16(const void* g, void* l) {
  __builtin_amdgcn_global_load_lds(
      (const __attribute__((address_space(1))) u32*)g,
      (__attribute__((address_space(3))) u32*)l, 16, 0, 0);
}

// ---------------- prepass: bf16 swizzled 32-key tile images ----------------
// Per (b,hk,t) 16 KiB image:
//  K part: row r(32) x 16 slots of 16B; phys slot p holds K[t*32+r][8*(p^(r&15))..+8)
//  V part: row d(128) x 4 slots of 16B; phys slot p holds V[t*32+8*(p^(d&3))+j][d]
__global__ __launch_bounds__(256)
void prepass(const float* __restrict__ kg, const float* __restrict__ vg,
             bf16_t* __restrict__ ws) {
  const int blk = blockIdx.x;            // bh*NT + t
  const int bh = blk >> 6, t = blk & 63;
  const float* ksrc = kg + ((size_t)bh * SQ + (size_t)t * KT) * D;
  const float* vsrc = vg + ((size_t)bh * SQ + (size_t)t * KT) * D;
  bf16_t* kdst = ws + (size_t)blk * TILE_ELEM;
  bf16_t* vdst = kdst + KT * D;
  const int tid = threadIdx.x;
#pragma unroll
  for (int i = 0; i < 2; ++i) {          // K: 512 16B chunks
    const int c = tid + 256 * i;
    const int r = c >> 4, p = c & 15, q = p ^ (r & 15);
    const float* s = ksrc + (size_t)r * D + 8 * q;
    f32x4v a = *(const f32x4v*)s;
    f32x4v b = *(const f32x4v*)(s + 4);
    bf16x8 w;
    w[0]=(bf16_t)a[0]; w[1]=(bf16_t)a[1]; w[2]=(bf16_t)a[2]; w[3]=(bf16_t)a[3];
    w[4]=(bf16_t)b[0]; w[5]=(bf16_t)b[1]; w[6]=(bf16_t)b[2]; w[7]=(bf16_t)b[3];
    *(bf16x8*)(kdst + (size_t)r * D + 8 * p) = w;
  }
#pragma unroll
  for (int i = 0; i < 2; ++i) {          // V^T: 512 16B chunks
    const int c = tid + 256 * i;
    const int d = c >> 2, p = c & 3, q = p ^ (d & 3);
    bf16x8 w;
#pragma unroll
    for (int j = 0; j < 8; ++j) w[j] = (bf16_t)vsrc[(size_t)(8 * q + j) * D + d];
    *(bf16x8*)(vdst + (size_t)d * KT + 8 * p) = w;
  }
}

// ---------------- main kernel ----------------------------------------------
__global__ __launch_bounds__(256, 5)
void fa5(const float* __restrict__ qg_, const bf16_t* __restrict__ ws,
         float* __restrict__ og_) {
  __shared__ __align__(16) char ldsraw[2 * TILE_BYTES];  // 32 KiB

  const int idx = blockIdx.x;            // 2048 blocks, heaviest first (LPT)
  const int g = idx >> 6, bh = idx & 63;
  const int qt = (NQT - 1) - g;          // qt = 31..0
  const int b = bh >> 5, h = bh & 31, hk = h >> 2;

  const int tid = threadIdx.x;
  const int wave = tid >> 6, lane = tid & 63;
  const int ln = lane & 31, hx = lane >> 5;
  const int rw = wave & 1;               // row-wave: rows q0+32*rw..+31
  const int kg = wave >> 1;              // key-group: 0 = [0,mid), 1 = [mid,end)

  const int q0 = qt * QT;
  const float* qg = qg_ + ((size_t)(b * HQ + h) * SQ + q0) * D;
  float*       og = og_ + ((size_t)(b * HQ + h) * SQ + q0) * D;
  const bf16_t* wsrc = ws + (size_t)(b * HK + hk) * NT * TILE_ELEM;

  const int ntg = qt + 1;                // 32-key tiles per group
  const int tbase = kg * ntg;            // group's first global tile index

  // staging: group's 16 KiB image = 16 chunks of 1 KiB; row-wave stages 8
  auto stage = [&](int tl) {
    const char* src = (const char*)(wsrc + (size_t)(tbase + tl) * TILE_ELEM);
    char* dst = ldsraw + (size_t)kg * TILE_BYTES;
#pragma unroll
    for (int i = 0; i < 8; ++i) {
      const int chunk = rw * 8 + i;
      gl_lds16(src + chunk * 1024 + lane * 16, dst + chunk * 1024);
    }
  };

  const float qscale = 0.08838834764831845f * 1.4426950408889634f;  // /sqrt(D)*log2e

  // Q frags: lane holds Q[qrow=q0+32rw+ln][d=16s+8hx+j]
  bf16x8 qf[8];
  {
    const float* qrp = qg + (size_t)(32 * rw + ln) * D + 8 * hx;
#pragma unroll
    for (int s = 0; s < 8; ++s) {
      f32x4v a = *(const f32x4v*)(qrp + 16 * s);
      f32x4v c = *(const f32x4v*)(qrp + 16 * s + 4);
      bf16x8 t;
      t[0]=(bf16_t)(a[0]*qscale); t[1]=(bf16_t)(a[1]*qscale);
      t[2]=(bf16_t)(a[2]*qscale); t[3]=(bf16_t)(a[3]*qscale);
      t[4]=(bf16_t)(c[0]*qscale); t[5]=(bf16_t)(c[1]*qscale);
      t[6]=(bf16_t)(c[2]*qscale); t[7]=(bf16_t)(c[3]*qscale);
      qf[s] = t;
    }
  }

  f32x16 Oa[4];
#pragma unroll
  for (int mb = 0; mb < 4; ++mb)
#pragma unroll
    for (int r = 0; r < 16; ++r) Oa[mb][r] = 0.f;
  float m = -1e30f, l = 0.f;

  const int wrow = q0 + 32 * rw;         // wave's first q row (32-aligned)

  for (int ti = 0; ti < ntg; ++ti) {
    stage(ti);
    __syncthreads();                     // vmcnt(0) drain -> tile resident

    const int kb = (tbase + ti) * KT;    // global key base of this tile
    if (kb <= wrow) {                    // wave-uniform causal activity
      const bf16_t* kbp = (const bf16_t*)(ldsraw + (size_t)kg * TILE_BYTES);
      const bf16_t* vbp = kbp + KT * D;

      // ---- S^T = K * Q^T (32 keys x 32 qrows) ----
      f32x16 sa;
#pragma unroll
      for (int r = 0; r < 16; ++r) sa[r] = 0.f;
      __builtin_amdgcn_s_setprio(1);
#pragma unroll
      for (int s = 0; s < 8; ++s) {
        const int cb = (2 * s + hx) ^ (ln & 15);
        bf16x8 kf = *(const bf16x8*)(kbp + ln * 128 + cb * 8);
        sa = __builtin_amdgcn_mfma_f32_32x32x16_bf16(kf, qf[s], sa, 0, 0, 0);
      }
      __builtin_amdgcn_s_setprio(0);

      // causal mask: only the diagonal tile
      if (kb == wrow) {
#pragma unroll
        for (int r = 0; r < 16; ++r) {
          const int kl = (r & 3) + 8 * (r >> 2) + 4 * hx;
          if (kl > ln) sa[r] = -1e30f;
        }
      }

      // ---- online softmax (lane-local row, log2 domain) ----
      float tm = -1e30f;
#pragma unroll
      for (int r = 0; r < 16; ++r) tm = fmaxf(tm, sa[r]);
      tm = fmaxf(tm, __shfl_xor(tm, 32, 64));
      if (__any(tm > m + 8.f)) {         // defer-max (T13)
        const float mn = fmaxf(m, tm);
        const float corr = fexp2(m - mn);
        m = mn; l *= corr;
#pragma unroll
        for (int mb = 0; mb < 4; ++mb)
#pragma unroll
          for (int r = 0; r < 16; ++r) Oa[mb][r] *= corr;
      }
#pragma unroll
      for (int r = 0; r < 16; ++r) sa[r] = fexp2(sa[r] - m);
      float ps = 0.f;
#pragma unroll
      for (int r = 0; r < 16; ++r) ps += sa[r];
      ps += __shfl_xor(ps, 32, 64);
      l += ps;

      // ---- pack P -> bf16 B-frags; send partner only what it needs ----
      u32x4 pa[2];
#pragma unroll
      for (int s2 = 0; s2 < 2; ++s2) {
        const u32 A0 = pkbf(sa[8*s2+0], sa[8*s2+1]);
        const u32 A1 = pkbf(sa[8*s2+2], sa[8*s2+3]);
        const u32 B0 = pkbf(sa[8*s2+4], sa[8*s2+5]);
        const u32 B1 = pkbf(sa[8*s2+6], sa[8*s2+7]);
        const u32 r0 = __shfl_xor(hx ? A0 : B0, 32, 64);
        const u32 r1 = __shfl_xor(hx ? A1 : B1, 32, 64);
        pa[s2][0] = hx ? r0 : A0;
        pa[s2][1] = hx ? r1 : A1;
        pa[s2][2] = hx ? B0 : r0;
        pa[s2][3] = hx ? B1 : r1;
      }

      // ---- O^T += V^T * P^T ----
      __builtin_amdgcn_s_setprio(1);
#pragma unroll
      for (int s2 = 0; s2 < 2; ++s2) {
#pragma unroll
        for (int mb = 0; mb < 4; ++mb) {
          const int d0 = ln + 32 * mb;
          const int cb = (2 * s2 + hx) ^ (d0 & 3);
          bf16x8 vf = *(const bf16x8*)(vbp + d0 * KT + cb * 8);
          Oa[mb] = __builtin_amdgcn_mfma_f32_32x32x16_bf16(
              vf, __builtin_bit_cast(bf16x8, pa[s2]), Oa[mb], 0, 0, 0);
        }
      }
      __builtin_amdgcn_s_setprio(0);
    }

    __syncthreads();                     // reads done before next overwrite
  }

  // ---- split-K combine: group B -> group A through LDS ----
  float* mlb = (float*)ldsraw;           // [rw][lane][2], 1 KiB
  if (kg) {
    mlb[(rw * 64 + lane) * 2]     = m;
    mlb[(rw * 64 + lane) * 2 + 1] = l;
  }
  __syncthreads();
  float mB = -1e30f, lB = 0.f;
  if (!kg) {
    mB = mlb[(rw * 64 + lane) * 2];
    lB = mlb[(rw * 64 + lane) * 2 + 1];
  }
  __syncthreads();
  float* ob = (float*)ldsraw;            // [rw][chunk 16][lane][4], 32 KiB
  if (kg) {
#pragma unroll
    for (int mb = 0; mb < 4; ++mb)
#pragma unroll
      for (int g2 = 0; g2 < 4; ++g2) {
        f32x4v v4;
        v4[0] = Oa[mb][4*g2+0]; v4[1] = Oa[mb][4*g2+1];
        v4[2] = Oa[mb][4*g2+2]; v4[3] = Oa[mb][4*g2+3];
        *(f32x4v*)(ob + rw * 4096 + (mb * 4 + g2) * 256 + lane * 4) = v4;
      }
  }
  __syncthreads();
  if (!kg) {
    const float M  = fmaxf(m, mB);
    const float cA = fexp2(m - M), cB = fexp2(mB - M);
    l = l * cA + lB * cB;
#pragma unroll
    for (int mb = 0; mb < 4; ++mb)
#pragma unroll
      for (int g2 = 0; g2 < 4; ++g2) {
        f32x4v v4 = *(const f32x4v*)(ob + rw * 4096 + (mb * 4 + g2) * 256 + lane * 4);
#pragma unroll
        for (int k = 0; k < 4; ++k)
          Oa[mb][4*g2+k] = Oa[mb][4*g2+k] * cA + v4[k] * cB;
      }
  }
  __syncthreads();                       // merge reads done before epi writes

  // ---- epilogue (group A only): LDS transpose, coalesced stores ----
  if (!kg) {
    const float inv = 1.f / l;
    float* wlds = (float*)ldsraw + rw * 2048;   // 8 KiB per row-wave
#pragma unroll
    for (int h2 = 0; h2 < 2; ++h2) {
#pragma unroll
      for (int mb2 = 0; mb2 < 2; ++mb2) {
        const int mb = 2 * h2 + mb2;
#pragma unroll
        for (int g2 = 0; g2 < 4; ++g2) {
          f32x4v v4;
          v4[0] = Oa[mb][4*g2+0] * inv; v4[1] = Oa[mb][4*g2+1] * inv;
          v4[2] = Oa[mb][4*g2+2] * inv; v4[3] = Oa[mb][4*g2+3] * inv;
          const int lslot = 2 * g2 + hx + 8 * mb2;
          const int pslot = lslot ^ (ln & 15);
          *(f32x4v*)(wlds + ln * 64 + pslot * 4) = v4;
        }
      }
      asm volatile("s_waitcnt lgkmcnt(0)" ::: "memory");
      __builtin_amdgcn_sched_barrier(0);
#pragma unroll
      for (int i = 0; i < 8; ++i) {
        const int q2 = 4 * i + (lane >> 4);
        const int lsl = lane & 15;
        const int psl = lsl ^ (q2 & 15);
        f32x4v v4 = *(const f32x4v*)(wlds + q2 * 64 + psl * 4);
        *(f32x4v*)(og + (size_t)(32 * rw + q2) * D + 64 * h2 + 4 * lsl) = v4;
      }
      __builtin_amdgcn_sched_barrier(0);
    }
  }
}

// ---------------- fallback (round-2 kernel, used if ws too small) ----------
namespace fb {
typedef float f32x4 __attribute__((ext_vector_type(4)));
constexpr int QT2 = 128, KT2 = 64;
constexpr int KELEM = 64 * 128, VELEM = 128 * 64, BUFE = KELEM + VELEM;

__device__ __forceinline__ u32 bfb(float f) {
  u32 u = __float_as_uint(f);
  u += 0x7fffu + ((u >> 16) & 1u);
  return u >> 16;
}
__device__ __forceinline__ bf16_t f2bf(float f) {
  unsigned short hs = (unsigned short)bfb(f);
  bf16_t b; __builtin_memcpy(&b, &hs, 2); return b;
}

__global__ __launch_bounds__(256, 2)
void fa2(const float* __restrict__ qg_, const float* __restrict__ kg_,
         const float* __restrict__ vg_, float* __restrict__ og_)
{
  __shared__ __align__(16) char ldsraw[2 * BUFE * 2];
  bf16_t* lds = (bf16_t*)ldsraw;
  const int qt = (int)gridDim.x - 1 - (int)blockIdx.x;
  const int bh = blockIdx.y;
  const int b = bh >> 5, h = bh & 31, hk = h >> 2;
  const int tid = threadIdx.x;
  const int wv = tid >> 6, lane = tid & 63;
  const int ln = lane & 31, hx = lane >> 5;
  const int q0 = qt * QT2;
  const float* qg = qg_ + ((size_t)(b * HQ + h) * SQ + q0) * D;
  const float* kg = kg_ + (size_t)(b * HK + hk) * SQ * D;
  const float* vg = vg_ + (size_t)(b * HK + hk) * SQ * D;
  float*       og = og_ + ((size_t)(b * HQ + h) * SQ + q0) * D;
  const float qscale = 0.08838834764831845f * 1.4426950408889634f;
  bf16x8 qf[8];
  {
    const float* qrow = qg + (size_t)(32 * wv + ln) * D;
#pragma unroll
    for (int s = 0; s < 8; ++s) {
      const float* p = qrow + 16 * s + 8 * hx;
      f32x4 a = *(const f32x4*)p;
      f32x4 c = *(const f32x4*)(p + 4);
      bf16x8 t;
      t[0]=f2bf(a[0]*qscale); t[1]=f2bf(a[1]*qscale);
      t[2]=f2bf(a[2]*qscale); t[3]=f2bf(a[3]*qscale);
      t[4]=f2bf(c[0]*qscale); t[5]=f2bf(c[1]*qscale);
      t[6]=f2bf(c[2]*qscale); t[7]=f2bf(c[3]*qscale);
      qf[s] = t;
    }
  }
  f32x16 Oa[4];
#pragma unroll
  for (int mb = 0; mb < 4; ++mb)
#pragma unroll
    for (int r = 0; r < 16; ++r) Oa[mb][r] = 0.f;
  float m = -1e30f, l = 0.f;
  const int qrow_g = q0 + 32 * wv + ln;
  const int wlast = q0 + 32 * wv + 31;
  const int kv_end = q0 + QT2;
  const int krow = tid >> 2, kq = tid & 3;
  const int vkh = tid & 7, vd4 = tid >> 3;
  f32x4 kst[8], vst[8];
  auto kstage_load = [&](int kb) {
    const float* src = kg + (size_t)(kb + krow) * D + kq * 32;
#pragma unroll
    for (int it = 0; it < 4; ++it) {
      kst[2*it]   = *(const f32x4*)(src + 8 * it);
      kst[2*it+1] = *(const f32x4*)(src + 8 * it + 4);
    }
  };
  auto kstage_write = [&](int buf) {
    bf16_t* kbp = lds + buf * BUFE;
#pragma unroll
    for (int it = 0; it < 4; ++it) {
      const int cb = (kq * 4 + it) ^ (krow & 7);
      bf16x8 w;
      w[0]=f2bf(kst[2*it][0]);   w[1]=f2bf(kst[2*it][1]);
      w[2]=f2bf(kst[2*it][2]);   w[3]=f2bf(kst[2*it][3]);
      w[4]=f2bf(kst[2*it+1][0]); w[5]=f2bf(kst[2*it+1][1]);
      w[6]=f2bf(kst[2*it+1][2]); w[7]=f2bf(kst[2*it+1][3]);
      *(bf16x8*)(kbp + krow * 128 + cb * 8) = w;
    }
  };
  auto vstage_load = [&](int kb) {
    const float* src = vg + (size_t)(kb + 8 * vkh) * D + 4 * vd4;
#pragma unroll
    for (int i = 0; i < 8; ++i) vst[i] = *(const f32x4*)(src + (size_t)i * D);
  };
  auto vstage_write = [&](int buf) {
    bf16_t* vbp = lds + buf * BUFE + KELEM;
#pragma unroll
    for (int j = 0; j < 4; ++j) {
      const int d = 4 * vd4 + j;
      const int cb = vkh ^ (d & 7);
      bf16x8 w;
#pragma unroll
      for (int i = 0; i < 8; ++i) w[i] = f2bf(vst[i][j]);
      *(bf16x8*)(vbp + d * 64 + cb * 8) = w;
    }
  };
  kstage_load(0); kstage_write(0);
  vstage_load(0); vstage_write(0);
  __syncthreads();
  int cur = 0;
  for (int kb = 0; kb < kv_end; kb += KT2) {
    const bool nx = (kb + KT2 < kv_end);
    const bool act = (kb <= wlast);
    if (nx) kstage_load(kb + KT2);
    u32x4 pa[4];
    if (act) {
      const bf16_t* kbp = lds + cur * BUFE;
      f32x16 s0, s1;
#pragma unroll
      for (int r = 0; r < 16; ++r) { s0[r] = 0.f; s1[r] = 0.f; }
#pragma unroll
      for (int s = 0; s < 8; ++s) {
        const int cb = (2 * s + hx) ^ (ln & 7);
        bf16x8 k0 = *(const bf16x8*)(kbp + ln * 128 + cb * 8);
        bf16x8 k1 = *(const bf16x8*)(kbp + (ln + 32) * 128 + cb * 8);
        s0 = __builtin_amdgcn_mfma_f32_32x32x16_bf16(k0, qf[s], s0, 0, 0, 0);
        s1 = __builtin_amdgcn_mfma_f32_32x32x16_bf16(k1, qf[s], s1, 0, 0, 0);
      }
      if (kb + 63 > q0 + 32 * wv) {
#pragma unroll
        for (int r = 0; r < 16; ++r) {
          const int kl = (r & 3) + 8 * (r >> 2) + 4 * hx;
          if (kb + kl > qrow_g)      s0[r] = -1e30f;
          if (kb + 32 + kl > qrow_g) s1[r] = -1e30f;
        }
      }
      float tm = -1e30f;
#pragma unroll
      for (int r = 0; r < 16; ++r) tm = fmaxf(tm, fmaxf(s0[r], s1[r]));
      tm = fmaxf(tm, __shfl_xor(tm, 32, 64));
      if (__any(tm > m + 8.f)) {
        const float mn = fmaxf(m, tm);
        const float corr = fexp2(m - mn);
        m = mn; l *= corr;
#pragma unroll
        for (int mb = 0; mb < 4; ++mb)
#pragma unroll
          for (int r = 0; r < 16; ++r) Oa[mb][r] *= corr;
      }
      f32x16 p0, p1;
#pragma unroll
      for (int r = 0; r < 16; ++r) {
        p0[r] = fexp2(s0[r] - m);
        p1[r] = fexp2(s1[r] - m);
      }
      float ps = 0.f;
#pragma unroll
      for (int r = 0; r < 16; ++r) ps += p0[r] + p1[r];
      ps += __shfl_xor(ps, 32, 64);
      l += ps;
#pragma unroll
      for (int kb2 = 0; kb2 < 2; ++kb2) {
        const f32x16& pp = kb2 ? p1 : p0;
#pragma unroll
        for (int s2 = 0; s2 < 2; ++s2) {
          const u32 A0 = pkbf(pp[8*s2+0], pp[8*s2+1]);
          const u32 A1 = pkbf(pp[8*s2+2], pp[8*s2+3]);
          const u32 B0 = pkbf(pp[8*s2+4], pp[8*s2+5]);
          const u32 B1 = pkbf(pp[8*s2+6], pp[8*s2+7]);
          const u32 sA0 = __shfl_xor(A0, 32, 64), sA1 = __shfl_xor(A1, 32, 64);
          const u32 sB0 = __shfl_xor(B0, 32, 64), sB1 = __shfl_xor(B1, 32, 64);
          const int ks = 2 * kb2 + s2;
          pa[ks][0] = hx ? sB0 : A0;
          pa[ks][1] = hx ? sB1 : A1;
          pa[ks][2] = hx ? B0 : sA0;
          pa[ks][3] = hx ? B1 : sA1;
        }
      }
    }
    if (nx) kstage_write(cur ^ 1);
    if (nx) vstage_load(kb + KT2);
    if (act) {
      const bf16_t* vbp = lds + cur * BUFE + KELEM;
#pragma unroll
      for (int mb = 0; mb < 4; ++mb) {
        const int d0 = ln + 32 * mb;
#pragma unroll
        for (int ks = 0; ks < 4; ++ks) {
          const int cb = (hx + 2 * ks) ^ (d0 & 7);
          bf16x8 vf = *(const bf16x8*)(vbp + d0 * 64 + cb * 8);
          Oa[mb] = __builtin_amdgcn_mfma_f32_32x32x16_bf16(
              vf, __builtin_bit_cast(bf16x8, pa[ks]), Oa[mb], 0, 0, 0);
        }
      }
    }
    if (nx) vstage_write(cur ^ 1);
    __syncthreads();
    cur ^= 1;
  }
  float* ol = (float*)ldsraw;
  float* wbase = ol + wv * 4096;
  const float inv = 1.f / l;
#pragma unroll
  for (int mb = 0; mb < 4; ++mb) {
#pragma unroll
    for (int g = 0; g < 4; ++g) {
      f32x4 v4;
      v4[0] = Oa[mb][4*g+0]*inv; v4[1] = Oa[mb][4*g+1]*inv;
      v4[2] = Oa[mb][4*g+2]*inv; v4[3] = Oa[mb][4*g+3]*inv;
      const int chunk = (2 * g + hx + 8 * mb) ^ (ln & 7);
      *(f32x4*)(wbase + ln * 128 + chunk * 4) = v4;
    }
  }
  __syncthreads();
#pragma unroll
  for (int i = 0; i < 16; ++i) {
    const int q2 = 2 * i + hx;
    const int cs = ln ^ (q2 & 7);
    f32x4 v4 = *(const f32x4*)(wbase + q2 * 128 + cs * 4);
    *(f32x4*)(og + (size_t)(32 * wv + q2) * D + 4 * ln) = v4;
  }
}
}  // namespace fb

extern "C" void kernel_launch(void* const* d_in, const int* in_sizes, int n_in,
                              void* d_out, int out_size, void* d_ws, size_t ws_size,
                              hipStream_t stream) {
  const float* q = (const float*)d_in[0];
  const float* k = (const float*)d_in[1];
  const float* v = (const float*)d_in[2];
  float* out = (float*)d_out;
  if (ws_size >= WS_NEED) {
    prepass<<<dim3(B_ * HK * NT), 256, 0, stream>>>(k, v, (bf16_t*)d_ws);
    fa5<<<dim3(NQT * 64), 256, 0, stream>>>(q, (const bf16_t*)d_ws, out);
  } else {
    fb::fa2<<<dim3(SQ / fb::QT2, B_ * HQ), 256, 0, stream>>>(q, k, v, out);
  }
}

// Round 6
// 147.789 us; speedup vs baseline: 3.3223x; 3.3223x over previous
//
#include <hip/hip_runtime.h>

// Causal GQA flash-attention fwd, fp32 I/O, bf16 32x32x16 MFMA.
// Prepass: K/V fp32 -> bf16 swizzled 32-key tile images in d_ws (once).
// Main: 768 PERSISTENT 4-wave blocks (3/CU), dynamic LPT item queue via
// atomic counter; per item (qt,bh): QT=128 rows (32/wave), KT=32 tiles,
// 3-buffer global_load_lds staging with counted vmcnt(4) + raw s_barrier
// (loads stay in flight across barriers), swapped-operand S^T=K*Q^T and
// O^T=V^T*P^T so softmax/rescale are lane-local.

typedef __bf16 bf16_t;
typedef __bf16 bf16x2 __attribute__((ext_vector_type(2)));
typedef __bf16 bf16x8 __attribute__((ext_vector_type(8)));
typedef float f32x4v __attribute__((ext_vector_type(4)));
typedef float f32x16 __attribute__((ext_vector_type(16)));
typedef unsigned int u32;
typedef u32 u32x4 __attribute__((ext_vector_type(4)));

constexpr int B_ = 2, HQ = 32, HK = 8, SQ = 2048, D = 128;
constexpr int QT = 128, KT = 32;
constexpr int NQT = SQ / QT;                  // 16 q-tiles
constexpr int NT = SQ / KT;                   // 64 kv tiles per (b,hk)
constexpr int NITEM = NQT * 64;               // 1024 work items
constexpr int NBLK = 768;                     // persistent blocks (3/CU)
constexpr int TILE_ELEM = KT * D * 2;         // 8192 bf16 = K(4096) + V(4096)
constexpr size_t TILE_BYTES = TILE_ELEM * 2;  // 16 KiB
constexpr size_t WS_IMG = (size_t)B_ * HK * NT * TILE_BYTES;  // 16 MiB
constexpr size_t WS_NEED = WS_IMG + 64;       // + atomic counter

__device__ __forceinline__ u32 pkbf(float a, float b) {  // f32x2 -> bf16x2
  bf16x2 t; t[0] = (bf16_t)a; t[1] = (bf16_t)b;
  return __builtin_bit_cast(u32, t);
}
__device__ __forceinline__ float fexp2(float x) { return __builtin_exp2f(x); }

__device__ __forceinline__ void gl_lds16(const void* g, void* l) {
  __builtin_amdgcn_global_load_lds(
      (const __attribute__((address_space(1))) u32*)g,
      (__attribute__((address_space(3))) u32*)l, 16, 0, 0);
}

// ---------------- prepass: bf16 swizzled 32-key tile images ----------------
// Per (b,hk,t) 16 KiB image:
//  K part: row r(32) x 16 slots of 16B; phys slot p holds K[t*32+r][8*(p^(r&15))..+8)
//  V part: row d(128) x 4 slots of 16B; phys slot p holds V[t*32+8*(p^(d&3))+j][d]
__global__ __launch_bounds__(256)
void prepass(const float* __restrict__ kg, const float* __restrict__ vg,
             bf16_t* __restrict__ ws) {
  const int blk = blockIdx.x;            // bh*NT + t
  const int bh = blk >> 6, t = blk & 63;
  const float* ksrc = kg + ((size_t)bh * SQ + (size_t)t * KT) * D;
  const float* vsrc = vg + ((size_t)bh * SQ + (size_t)t * KT) * D;
  bf16_t* kdst = ws + (size_t)blk * TILE_ELEM;
  bf16_t* vdst = kdst + KT * D;
  const int tid = threadIdx.x;
#pragma unroll
  for (int i = 0; i < 2; ++i) {          // K: 512 16B chunks
    const int c = tid + 256 * i;
    const int r = c >> 4, p = c & 15, q = p ^ (r & 15);
    const float* s = ksrc + (size_t)r * D + 8 * q;
    f32x4v a = *(const f32x4v*)s;
    f32x4v b = *(const f32x4v*)(s + 4);
    bf16x8 w;
    w[0]=(bf16_t)a[0]; w[1]=(bf16_t)a[1]; w[2]=(bf16_t)a[2]; w[3]=(bf16_t)a[3];
    w[4]=(bf16_t)b[0]; w[5]=(bf16_t)b[1]; w[6]=(bf16_t)b[2]; w[7]=(bf16_t)b[3];
    *(bf16x8*)(kdst + (size_t)r * D + 8 * p) = w;
  }
#pragma unroll
  for (int i = 0; i < 2; ++i) {          // V^T: 512 16B chunks
    const int c = tid + 256 * i;
    const int d = c >> 2, p = c & 3, q = p ^ (d & 3);
    bf16x8 w;
#pragma unroll
    for (int j = 0; j < 8; ++j) w[j] = (bf16_t)vsrc[(size_t)(8 * q + j) * D + d];
    *(bf16x8*)(vdst + (size_t)d * KT + 8 * p) = w;
  }
}

// ---------------- main kernel (persistent) ---------------------------------
__global__ __launch_bounds__(256, 3)
void fa6(const float* __restrict__ qg_, const bf16_t* __restrict__ ws,
         float* __restrict__ og_, int* __restrict__ cnt) {
  __shared__ __align__(16) char ldsraw[3 * TILE_BYTES];  // 48 KiB, 3 buffers
  __shared__ int item_s;

  const int tid = threadIdx.x;
  const int wv = tid >> 6, lane = tid & 63;
  const int ln = lane & 31, hx = lane >> 5;
  const float qscale = 0.08838834764831845f * 1.4426950408889634f;  // /sqrt(D)*log2e

  for (;;) {
    if (tid == 0) item_s = atomicAdd(cnt, 1);
    __syncthreads();                     // item visible; prev epilogue done
    const int it = item_s;
    if (it >= NITEM) break;

    const int qt = (NQT - 1) - (it >> 6);  // heavy q-tiles first (LPT)
    const int bh = it & 63;
    const int b = bh >> 5, h = bh & 31, hk = h >> 2;
    const int q0 = qt * QT;
    const float* qg = qg_ + ((size_t)(b * HQ + h) * SQ + q0) * D;
    float*       og = og_ + ((size_t)(b * HQ + h) * SQ + q0) * D;
    const bf16_t* wsrc = ws + (size_t)(b * HK + hk) * NT * TILE_ELEM;
    const int ntile = q0 / KT + 4;       // 4..64 tiles
    const int wrow = q0 + 32 * wv;       // wave's first q row

    auto stage = [&](int tl, int buf) {
      const char* src = (const char*)(wsrc + (size_t)tl * TILE_ELEM);
      char* dst = ldsraw + (size_t)buf * TILE_BYTES;
#pragma unroll
      for (int i = 0; i < 4; ++i) {      // wave stages 4 x 1 KiB chunks
        const int chunk = 4 * wv + i;
        gl_lds16(src + chunk * 1024 + lane * 16, dst + chunk * 1024);
      }
    };

    stage(0, 0);                         // FIFO: st0(4), qf(16), st1(4)

    // Q frags: lane holds Q[qrow=q0+32wv+ln][d=16s+8hx+j]
    bf16x8 qf[8];
    {
      const float* qrp = qg + (size_t)(32 * wv + ln) * D + 8 * hx;
#pragma unroll
      for (int s = 0; s < 8; ++s) {
        f32x4v a = *(const f32x4v*)(qrp + 16 * s);
        f32x4v c = *(const f32x4v*)(qrp + 16 * s + 4);
        bf16x8 t;
        t[0]=(bf16_t)(a[0]*qscale); t[1]=(bf16_t)(a[1]*qscale);
        t[2]=(bf16_t)(a[2]*qscale); t[3]=(bf16_t)(a[3]*qscale);
        t[4]=(bf16_t)(c[0]*qscale); t[5]=(bf16_t)(c[1]*qscale);
        t[6]=(bf16_t)(c[2]*qscale); t[7]=(bf16_t)(c[3]*qscale);
        qf[s] = t;
      }
    }
    stage(1, 1);

    f32x16 Oa[4];
#pragma unroll
    for (int mb = 0; mb < 4; ++mb)
#pragma unroll
      for (int r = 0; r < 16; ++r) Oa[mb][r] = 0.f;
    float m = -1e30f, l = 0.f;

    int cur = 0;
    for (int t = 0; t < ntile; ++t) {
      // counted wait: own tile-t chunks done; tile-(t+1) chunks stay in flight
      if (t + 1 < ntile) { asm volatile("s_waitcnt vmcnt(4)" ::: "memory"); }
      else               { asm volatile("s_waitcnt vmcnt(0)" ::: "memory"); }
      __builtin_amdgcn_sched_barrier(0);
      __builtin_amdgcn_s_barrier();      // raw: no vmcnt-0 drain
      __builtin_amdgcn_sched_barrier(0);

      if (t + 2 < ntile) {               // prefetch 2 ahead into freed buffer
        const int sb = (cur == 0) ? 2 : cur - 1;  // (cur+2)%3
        stage(t + 2, sb);
      }

      const int kb = t * KT;
      if (kb <= wrow) {                  // wave-uniform causal activity
        const bf16_t* kbp = (const bf16_t*)(ldsraw + (size_t)cur * TILE_BYTES);
        const bf16_t* vbp = kbp + KT * D;

        // ---- S^T = K * Q^T (32 keys x 32 qrows) ----
        f32x16 sa;
#pragma unroll
        for (int r = 0; r < 16; ++r) sa[r] = 0.f;
        __builtin_amdgcn_s_setprio(1);
#pragma unroll
        for (int s = 0; s < 8; ++s) {
          const int cb = (2 * s + hx) ^ (ln & 15);
          bf16x8 kf = *(const bf16x8*)(kbp + ln * 128 + cb * 8);
          sa = __builtin_amdgcn_mfma_f32_32x32x16_bf16(kf, qf[s], sa, 0, 0, 0);
        }
        __builtin_amdgcn_s_setprio(0);

        // causal mask: only the diagonal tile
        if (kb == wrow) {
#pragma unroll
          for (int r = 0; r < 16; ++r) {
            const int kl = (r & 3) + 8 * (r >> 2) + 4 * hx;
            if (kl > ln) sa[r] = -1e30f;
          }
        }

        // ---- online softmax (lane-local row, log2 domain) ----
        float tm = -1e30f;
#pragma unroll
        for (int r = 0; r < 16; ++r) tm = fmaxf(tm, sa[r]);
        tm = fmaxf(tm, __shfl_xor(tm, 32, 64));
        if (__any(tm > m + 8.f)) {       // defer-max (T13)
          const float mn = fmaxf(m, tm);
          const float corr = fexp2(m - mn);
          m = mn; l *= corr;
#pragma unroll
          for (int mb = 0; mb < 4; ++mb)
#pragma unroll
            for (int r = 0; r < 16; ++r) Oa[mb][r] *= corr;
        }
#pragma unroll
        for (int r = 0; r < 16; ++r) sa[r] = fexp2(sa[r] - m);
        float ps = 0.f;
#pragma unroll
        for (int r = 0; r < 16; ++r) ps += sa[r];
        ps += __shfl_xor(ps, 32, 64);
        l += ps;

        // ---- pack P -> bf16 B-frags; send partner only what it needs ----
        u32x4 pa[2];
#pragma unroll
        for (int s2 = 0; s2 < 2; ++s2) {
          const u32 A0 = pkbf(sa[8*s2+0], sa[8*s2+1]);
          const u32 A1 = pkbf(sa[8*s2+2], sa[8*s2+3]);
          const u32 B0 = pkbf(sa[8*s2+4], sa[8*s2+5]);
          const u32 B1 = pkbf(sa[8*s2+6], sa[8*s2+7]);
          const u32 r0 = __shfl_xor(hx ? A0 : B0, 32, 64);
          const u32 r1 = __shfl_xor(hx ? A1 : B1, 32, 64);
          pa[s2][0] = hx ? r0 : A0;
          pa[s2][1] = hx ? r1 : A1;
          pa[s2][2] = hx ? B0 : r0;
          pa[s2][3] = hx ? B1 : r1;
        }

        // ---- O^T += V^T * P^T ----
        __builtin_amdgcn_s_setprio(1);
#pragma unroll
        for (int s2 = 0; s2 < 2; ++s2) {
#pragma unroll
          for (int mb = 0; mb < 4; ++mb) {
            const int d0 = ln + 32 * mb;
            const int cb = (2 * s2 + hx) ^ (d0 & 3);
            bf16x8 vf = *(const bf16x8*)(vbp + d0 * KT + cb * 8);
            Oa[mb] = __builtin_amdgcn_mfma_f32_32x32x16_bf16(
                vf, __builtin_bit_cast(bf16x8, pa[s2]), Oa[mb], 0, 0, 0);
          }
        }
        __builtin_amdgcn_s_setprio(0);
      }

      cur = (cur == 2) ? 0 : cur + 1;
    }

    // all own DMA drained (last iter waited vmcnt(0)); drain own ds_reads,
    // then block-wide barrier before reusing LDS as epilogue scratch
    asm volatile("s_waitcnt lgkmcnt(0)" ::: "memory");
    __builtin_amdgcn_s_barrier();
    __builtin_amdgcn_sched_barrier(0);

    // ---- epilogue: per-wave LDS transpose (8 KiB each), coalesced stores ----
    const float inv = 1.f / l;
    float* wlds = (float*)ldsraw + wv * 2048;
#pragma unroll
    for (int h2 = 0; h2 < 2; ++h2) {
#pragma unroll
      for (int mb2 = 0; mb2 < 2; ++mb2) {
        const int mb = 2 * h2 + mb2;
#pragma unroll
        for (int g2 = 0; g2 < 4; ++g2) {
          f32x4v v4;
          v4[0] = Oa[mb][4*g2+0] * inv; v4[1] = Oa[mb][4*g2+1] * inv;
          v4[2] = Oa[mb][4*g2+2] * inv; v4[3] = Oa[mb][4*g2+3] * inv;
          const int lslot = 2 * g2 + hx + 8 * mb2;
          const int pslot = lslot ^ (ln & 15);
          *(f32x4v*)(wlds + ln * 64 + pslot * 4) = v4;
        }
      }
      asm volatile("s_waitcnt lgkmcnt(0)" ::: "memory");
      __builtin_amdgcn_sched_barrier(0);
#pragma unroll
      for (int i = 0; i < 8; ++i) {
        const int q2 = 4 * i + (lane >> 4);
        const int lsl = lane & 15;
        const int psl = lsl ^ (q2 & 15);
        f32x4v v4 = *(const f32x4v*)(wlds + q2 * 64 + psl * 4);
        *(f32x4v*)(og + (size_t)(32 * wv + q2) * D + 64 * h2 + 4 * lsl) = v4;
      }
      __builtin_amdgcn_sched_barrier(0);
    }
  }
}

// ---------------- fallback (round-2 kernel, used if ws too small) ----------
namespace fb {
typedef float f32x4 __attribute__((ext_vector_type(4)));
constexpr int QT2 = 128, KT2 = 64;
constexpr int KELEM = 64 * 128, VELEM = 128 * 64, BUFE = KELEM + VELEM;

__device__ __forceinline__ u32 bfb(float f) {
  u32 u = __float_as_uint(f);
  u += 0x7fffu + ((u >> 16) & 1u);
  return u >> 16;
}
__device__ __forceinline__ bf16_t f2bf(float f) {
  unsigned short hs = (unsigned short)bfb(f);
  bf16_t b; __builtin_memcpy(&b, &hs, 2); return b;
}

__global__ __launch_bounds__(256, 2)
void fa2(const float* __restrict__ qg_, const float* __restrict__ kg_,
         const float* __restrict__ vg_, float* __restrict__ og_)
{
  __shared__ __align__(16) char ldsraw[2 * BUFE * 2];
  bf16_t* lds = (bf16_t*)ldsraw;
  const int qt = (int)gridDim.x - 1 - (int)blockIdx.x;
  const int bh = blockIdx.y;
  const int b = bh >> 5, h = bh & 31, hk = h >> 2;
  const int tid = threadIdx.x;
  const int wv = tid >> 6, lane = tid & 63;
  const int ln = lane & 31, hx = lane >> 5;
  const int q0 = qt * QT2;
  const float* qg = qg_ + ((size_t)(b * HQ + h) * SQ + q0) * D;
  const float* kg = kg_ + (size_t)(b * HK + hk) * SQ * D;
  const float* vg = vg_ + (size_t)(b * HK + hk) * SQ * D;
  float*       og = og_ + ((size_t)(b * HQ + h) * SQ + q0) * D;
  const float qscale = 0.08838834764831845f * 1.4426950408889634f;
  bf16x8 qf[8];
  {
    const float* qrow = qg + (size_t)(32 * wv + ln) * D;
#pragma unroll
    for (int s = 0; s < 8; ++s) {
      const float* p = qrow + 16 * s + 8 * hx;
      f32x4 a = *(const f32x4*)p;
      f32x4 c = *(const f32x4*)(p + 4);
      bf16x8 t;
      t[0]=f2bf(a[0]*qscale); t[1]=f2bf(a[1]*qscale);
      t[2]=f2bf(a[2]*qscale); t[3]=f2bf(a[3]*qscale);
      t[4]=f2bf(c[0]*qscale); t[5]=f2bf(c[1]*qscale);
      t[6]=f2bf(c[2]*qscale); t[7]=f2bf(c[3]*qscale);
      qf[s] = t;
    }
  }
  f32x16 Oa[4];
#pragma unroll
  for (int mb = 0; mb < 4; ++mb)
#pragma unroll
    for (int r = 0; r < 16; ++r) Oa[mb][r] = 0.f;
  float m = -1e30f, l = 0.f;
  const int qrow_g = q0 + 32 * wv + ln;
  const int wlast = q0 + 32 * wv + 31;
  const int kv_end = q0 + QT2;
  const int krow = tid >> 2, kq = tid & 3;
  const int vkh = tid & 7, vd4 = tid >> 3;
  f32x4 kst[8], vst[8];
  auto kstage_load = [&](int kb) {
    const float* src = kg + (size_t)(kb + krow) * D + kq * 32;
#pragma unroll
    for (int it = 0; it < 4; ++it) {
      kst[2*it]   = *(const f32x4*)(src + 8 * it);
      kst[2*it+1] = *(const f32x4*)(src + 8 * it + 4);
    }
  };
  auto kstage_write = [&](int buf) {
    bf16_t* kbp = lds + buf * BUFE;
#pragma unroll
    for (int it = 0; it < 4; ++it) {
      const int cb = (kq * 4 + it) ^ (krow & 7);
      bf16x8 w;
      w[0]=f2bf(kst[2*it][0]);   w[1]=f2bf(kst[2*it][1]);
      w[2]=f2bf(kst[2*it][2]);   w[3]=f2bf(kst[2*it][3]);
      w[4]=f2bf(kst[2*it+1][0]); w[5]=f2bf(kst[2*it+1][1]);
      w[6]=f2bf(kst[2*it+1][2]); w[7]=f2bf(kst[2*it+1][3]);
      *(bf16x8*)(kbp + krow * 128 + cb * 8) = w;
    }
  };
  auto vstage_load = [&](int kb) {
    const float* src = vg + (size_t)(kb + 8 * vkh) * D + 4 * vd4;
#pragma unroll
    for (int i = 0; i < 8; ++i) vst[i] = *(const f32x4*)(src + (size_t)i * D);
  };
  auto vstage_write = [&](int buf) {
    bf16_t* vbp = lds + buf * BUFE + KELEM;
#pragma unroll
    for (int j = 0; j < 4; ++j) {
      const int d = 4 * vd4 + j;
      const int cb = vkh ^ (d & 7);
      bf16x8 w;
#pragma unroll
      for (int i = 0; i < 8; ++i) w[i] = f2bf(vst[i][j]);
      *(bf16x8*)(vbp + d * 64 + cb * 8) = w;
    }
  };
  kstage_load(0); kstage_write(0);
  vstage_load(0); vstage_write(0);
  __syncthreads();
  int cur = 0;
  for (int kb = 0; kb < kv_end; kb += KT2) {
    const bool nx = (kb + KT2 < kv_end);
    const bool act = (kb <= wlast);
    if (nx) kstage_load(kb + KT2);
    u32x4 pa[4];
    if (act) {
      const bf16_t* kbp = lds + cur * BUFE;
      f32x16 s0, s1;
#pragma unroll
      for (int r = 0; r < 16; ++r) { s0[r] = 0.f; s1[r] = 0.f; }
#pragma unroll
      for (int s = 0; s < 8; ++s) {
        const int cb = (2 * s + hx) ^ (ln & 7);
        bf16x8 k0 = *(const bf16x8*)(kbp + ln * 128 + cb * 8);
        bf16x8 k1 = *(const bf16x8*)(kbp + (ln + 32) * 128 + cb * 8);
        s0 = __builtin_amdgcn_mfma_f32_32x32x16_bf16(k0, qf[s], s0, 0, 0, 0);
        s1 = __builtin_amdgcn_mfma_f32_32x32x16_bf16(k1, qf[s], s1, 0, 0, 0);
      }
      if (kb + 63 > q0 + 32 * wv) {
#pragma unroll
        for (int r = 0; r < 16; ++r) {
          const int kl = (r & 3) + 8 * (r >> 2) + 4 * hx;
          if (kb + kl > qrow_g)      s0[r] = -1e30f;
          if (kb + 32 + kl > qrow_g) s1[r] = -1e30f;
        }
      }
      float tm = -1e30f;
#pragma unroll
      for (int r = 0; r < 16; ++r) tm = fmaxf(tm, fmaxf(s0[r], s1[r]));
      tm = fmaxf(tm, __shfl_xor(tm, 32, 64));
      if (__any(tm > m + 8.f)) {
        const float mn = fmaxf(m, tm);
        const float corr = fexp2(m - mn);
        m = mn; l *= corr;
#pragma unroll
        for (int mb = 0; mb < 4; ++mb)
#pragma unroll
          for (int r = 0; r < 16; ++r) Oa[mb][r] *= corr;
      }
      f32x16 p0, p1;
#pragma unroll
      for (int r = 0; r < 16; ++r) {
        p0[r] = fexp2(s0[r] - m);
        p1[r] = fexp2(s1[r] - m);
      }
      float ps = 0.f;
#pragma unroll
      for (int r = 0; r < 16; ++r) ps += p0[r] + p1[r];
      ps += __shfl_xor(ps, 32, 64);
      l += ps;
#pragma unroll
      for (int kb2 = 0; kb2 < 2; ++kb2) {
        const f32x16& pp = kb2 ? p1 : p0;
#pragma unroll
        for (int s2 = 0; s2 < 2; ++s2) {
          const u32 A0 = pkbf(pp[8*s2+0], pp[8*s2+1]);
          const u32 A1 = pkbf(pp[8*s2+2], pp[8*s2+3]);
          const u32 B0 = pkbf(pp[8*s2+4], pp[8*s2+5]);
          const u32 B1 = pkbf(pp[8*s2+6], pp[8*s2+7]);
          const u32 sA0 = __shfl_xor(A0, 32, 64), sA1 = __shfl_xor(A1, 32, 64);
          const u32 sB0 = __shfl_xor(B0, 32, 64), sB1 = __shfl_xor(B1, 32, 64);
          const int ks = 2 * kb2 + s2;
          pa[ks][0] = hx ? sB0 : A0;
          pa[ks][1] = hx ? sB1 : A1;
          pa[ks][2] = hx ? B0 : sA0;
          pa[ks][3] = hx ? B1 : sA1;
        }
      }
    }
    if (nx) kstage_write(cur ^ 1);
    if (nx) vstage_load(kb + KT2);
    if (act) {
      const bf16_t* vbp = lds + cur * BUFE + KELEM;
#pragma unroll
      for (int mb = 0; mb < 4; ++mb) {
        const int d0 = ln + 32 * mb;
#pragma unroll
        for (int ks = 0; ks < 4; ++ks) {
          const int cb = (hx + 2 * ks) ^ (d0 & 7);
          bf16x8 vf = *(const bf16x8*)(vbp + d0 * 64 + cb * 8);
          Oa[mb] = __builtin_amdgcn_mfma_f32_32x32x16_bf16(
              vf, __builtin_bit_cast(bf16x8, pa[ks]), Oa[mb], 0, 0, 0);
        }
      }
    }
    if (nx) vstage_write(cur ^ 1);
    __syncthreads();
    cur ^= 1;
  }
  float* ol = (float*)ldsraw;
  float* wbase = ol + wv * 4096;
  const float inv = 1.f / l;
#pragma unroll
  for (int mb = 0; mb < 4; ++mb) {
#pragma unroll
    for (int g = 0; g < 4; ++g) {
      f32x4 v4;
      v4[0] = Oa[mb][4*g+0]*inv; v4[1] = Oa[mb][4*g+1]*inv;
      v4[2] = Oa[mb][4*g+2]*inv; v4[3] = Oa[mb][4*g+3]*inv;
      const int chunk = (2 * g + hx + 8 * mb) ^ (ln & 7);
      *(f32x4*)(wbase + ln * 128 + chunk * 4) = v4;
    }
  }
  __syncthreads();
#pragma unroll
  for (int i = 0; i < 16; ++i) {
    const int q2 = 2 * i + hx;
    const int cs = ln ^ (q2 & 7);
    f32x4 v4 = *(const f32x4*)(wbase + q2 * 128 + cs * 4);
    *(f32x4*)(og + (size_t)(32 * wv + q2) * D + 4 * ln) = v4;
  }
}
}  // namespace fb

extern "C" void kernel_launch(void* const* d_in, const int* in_sizes, int n_in,
                              void* d_out, int out_size, void* d_ws, size_t ws_size,
                              hipStream_t stream) {
  const float* q = (const float*)d_in[0];
  const float* k = (const float*)d_in[1];
  const float* v = (const float*)d_in[2];
  float* out = (float*)d_out;
  if (ws_size >= WS_NEED) {
    int* cnt = (int*)((char*)d_ws + WS_IMG);
    hipMemsetAsync(cnt, 0, sizeof(int), stream);
    prepass<<<dim3(B_ * HK * NT), 256, 0, stream>>>(k, v, (bf16_t*)d_ws);
    fa6<<<dim3(NBLK), 256, 0, stream>>>(q, (const bf16_t*)d_ws, out, cnt);
  } else {
    fb::fa2<<<dim3(SQ / fb::QT2, B_ * HQ), 256, 0, stream>>>(q, k, v, out);
  }
}